// Round 1
// baseline (725.671 us; speedup 1.0000x reference)
//
#include <hip/hip_runtime.h>
#include <stdint.h>

// ---------------------------------------------------------------------------
// SelfAttnV3: qkv = x@Wqkv+b; S = Q@K^T/sqrt(D); p = softmax(S);
//             w2 = softmax(mask ? p : -1e20); out = (w2@V)@Wout + b_out
// Double-softmax identity: exp(-1e20-m)==0, p<=1 => w2 = mask*exp(p)/sum(mask*exp(p))
// All GEMMs bf16 MFMA (16x16x32), NT form (B given as [N,K] row-major).
// ---------------------------------------------------------------------------

#define NN 2048
#define DD 1024

typedef __attribute__((ext_vector_type(8))) __bf16 bf16x8;
typedef __attribute__((ext_vector_type(4))) float f32x4;
typedef __attribute__((ext_vector_type(8))) unsigned short us8;
typedef __attribute__((ext_vector_type(4))) unsigned short us4;

__device__ __forceinline__ unsigned short f2bf(float f) {
  unsigned u = __builtin_bit_cast(unsigned, f);
  return (unsigned short)((u + 0x7FFFu + ((u >> 16) & 1u)) >> 16);  // RNE
}
__device__ __forceinline__ float bf2f(unsigned short h) {
  unsigned u = ((unsigned)h) << 16;
  return __builtin_bit_cast(float, u);
}

// async global->LDS, 16B per lane. LDS dest must be wave-uniform base + lane*16.
__device__ __forceinline__ void async16(const void* g, void* l) {
  __builtin_amdgcn_global_load_lds(
      (__attribute__((address_space(1))) void*)(uintptr_t)g,
      (__attribute__((address_space(3))) void*)(uintptr_t)l,  // low 32b = LDS offset
      16, 0, 0);
}

// ---------------------------------------------------------------------------
// fp32 -> bf16 elementwise convert (vectorized)
// ---------------------------------------------------------------------------
__global__ __launch_bounds__(256) void cvt_bf16(const float* __restrict__ src,
                                                unsigned short* __restrict__ dst,
                                                long n) {
  long i = ((long)blockIdx.x * 256 + threadIdx.x) * 4;
  long stride = (long)gridDim.x * 256 * 4;
  for (; i < n; i += stride) {
    float4 v = *reinterpret_cast<const float4*>(src + i);
    us4 o;
    o[0] = f2bf(v.x); o[1] = f2bf(v.y); o[2] = f2bf(v.z); o[3] = f2bf(v.w);
    *reinterpret_cast<us4*>(dst + i) = o;
  }
}

// ---------------------------------------------------------------------------
// fp32 [rows,cols] -> bf16 [cols,rows] transpose (for weights)
// ---------------------------------------------------------------------------
__global__ __launch_bounds__(256) void transpose_cvt(const float* __restrict__ src,
                                                     unsigned short* __restrict__ dst,
                                                     int rows, int cols) {
  __shared__ float t[32][33];
  const int tx = threadIdx.x & 31, ty = threadIdx.x >> 5;
  const int c0 = blockIdx.x * 32, r0 = blockIdx.y * 32;
#pragma unroll
  for (int i = 0; i < 32; i += 8)
    t[ty + i][tx] = src[(long)(r0 + ty + i) * cols + (c0 + tx)];
  __syncthreads();
#pragma unroll
  for (int i = 0; i < 32; i += 8)
    dst[(long)(c0 + ty + i) * rows + (r0 + tx)] = f2bf(t[tx][ty + i]);
}

// ---------------------------------------------------------------------------
// V slice of qkv [per-batch 2048 x 1024, row stride 3072] -> vt [1024 x 2048]
// ---------------------------------------------------------------------------
__global__ __launch_bounds__(256) void transpose_v(const unsigned short* __restrict__ qkv,
                                                   unsigned short* __restrict__ vt) {
  __shared__ unsigned short t[32][33];
  const int tx = threadIdx.x & 31, ty = threadIdx.x >> 5;
  const int c0 = blockIdx.x * 32, r0 = blockIdx.y * 32;  // c: d (1024), r: n (2048)
  const long z = blockIdx.z;
  const unsigned short* src = qkv + z * (long)NN * 3072 + 2 * DD;
  unsigned short* dst = vt + z * (long)DD * NN;
#pragma unroll
  for (int i = 0; i < 32; i += 8)
    t[ty + i][tx] = src[(long)(r0 + ty + i) * 3072 + (c0 + tx)];
  __syncthreads();
#pragma unroll
  for (int i = 0; i < 32; i += 8)
    dst[(long)(c0 + ty + i) * NN + (r0 + tx)] = t[tx][ty + i];
}

// ---------------------------------------------------------------------------
// NT bf16 GEMM, m97 structure: C[M,N] = A[M,K] @ B[N,K]^T (*scale) (+bias)
// 128x128 tile, BK=32, 256 threads = 4 waves (2x2 of 64x64), single-buffered LDS,
// global_load_lds width-16 staging, mfma_f32_16x16x32_bf16.
// ---------------------------------------------------------------------------
template <bool BIAS, bool OUTF32>
__global__ __launch_bounds__(256) void gemm_bt(
    const unsigned short* __restrict__ A, long lda, long sA,
    const unsigned short* __restrict__ B, long ldb, long sB,
    void* __restrict__ Cv, long ldc, long sC,
    const float* __restrict__ bias, int K, float scale) {
  __shared__ __attribute__((aligned(16))) unsigned short As[128 * 32];
  __shared__ __attribute__((aligned(16))) unsigned short Bs[128 * 32];
  const int tid = threadIdx.x;
  const long bm = blockIdx.y, bn = blockIdx.x, bz = blockIdx.z;
  A += bz * sA + bm * 128 * lda;
  B += bz * sB + bn * 128 * ldb;

  // staging: chunk c in [0,512): row=c>>2, k8=(c&3)*8; thread t does c=t and c=t+256
  const int r0 = tid >> 2;
  const int kc8 = (tid & 3) * 8;
  const unsigned short* Ar0 = A + (long)r0 * lda + kc8;
  const unsigned short* Ar1 = A + (long)(r0 + 64) * lda + kc8;
  const unsigned short* Br0 = B + (long)r0 * ldb + kc8;
  const unsigned short* Br1 = B + (long)(r0 + 64) * ldb + kc8;
  unsigned short* lA0 = &As[tid * 8];
  unsigned short* lA1 = &As[(tid + 256) * 8];
  unsigned short* lB0 = &Bs[tid * 8];
  unsigned short* lB1 = &Bs[(tid + 256) * 8];

  f32x4 acc[4][4] = {};
  const int lane = tid & 63;
  const int wm = (tid >> 7) * 64;         // wave row (2x2 wave grid)
  const int wn = ((tid >> 6) & 1) * 64;   // wave col
  const int fr = lane & 15;               // frag row (A) / col (B)
  const int kq = (lane >> 4) * 8;         // frag k offset (quad*8, verified m120)

  for (int kt = 0; kt < K; kt += 32) {
    async16(Ar0 + kt, lA0);
    async16(Ar1 + kt, lA1);
    async16(Br0 + kt, lB0);
    async16(Br1 + kt, lB1);
    __syncthreads();  // compiler emits vmcnt(0) drain before barrier
    bf16x8 a[4], b[4];
#pragma unroll
    for (int i = 0; i < 4; i++)
      a[i] = *reinterpret_cast<const bf16x8*>(&As[(wm + i * 16 + fr) * 32 + kq]);
#pragma unroll
    for (int i = 0; i < 4; i++)
      b[i] = *reinterpret_cast<const bf16x8*>(&Bs[(wn + i * 16 + fr) * 32 + kq]);
#pragma unroll
    for (int mi = 0; mi < 4; mi++)
#pragma unroll
      for (int ni = 0; ni < 4; ni++)
        acc[mi][ni] = __builtin_amdgcn_mfma_f32_16x16x32_bf16(a[mi], b[ni], acc[mi][ni], 0, 0, 0);
    __syncthreads();
  }

  // epilogue: C/D layout col=lane&15, row=(lane>>4)*4+reg (m89-verified)
  const int cr = (lane >> 4) * 4;
  float* Cf = (float*)Cv;
  unsigned short* Ch = (unsigned short*)Cv;
  const long crow0 = bm * 128 + wm;
  const long ccol0 = bn * 128 + wn;
#pragma unroll
  for (int ni = 0; ni < 4; ni++) {
    const long gc = ccol0 + ni * 16 + fr;
    const float bv = BIAS ? bias[gc] : 0.0f;
#pragma unroll
    for (int mi = 0; mi < 4; mi++) {
      const long gr = crow0 + mi * 16 + cr;
#pragma unroll
      for (int r = 0; r < 4; r++) {
        float v = acc[mi][ni][r] * scale + bv;
        long idx = bz * sC + (gr + r) * ldc + gc;
        if (OUTF32) Cf[idx] = v;
        else        Ch[idx] = f2bf(v);
      }
    }
  }
}

// ---------------------------------------------------------------------------
// Fused double softmax per row: p = softmax(s); w2 = mask*exp(p)/sum(mask*exp(p))
// One block (256 thr) per row; 8 elements/thread in registers.
// ---------------------------------------------------------------------------
__global__ __launch_bounds__(256) void softmax2(const unsigned short* __restrict__ S,
                                                const int* __restrict__ mask,
                                                unsigned short* __restrict__ W2,
                                                int b0) {
  const int q = blockIdx.x;
  const int zb = blockIdx.y;
  const int tid = threadIdx.x;
  const int lane = tid & 63, wave = tid >> 6;
  const long rl = ((long)zb * NN + q) * NN;
  const unsigned short* srow = S + rl;
  unsigned short* wrow = W2 + rl;
  const int* mrow = mask + ((long)(b0 + zb) * NN + q) * NN;

  us8 sv = *reinterpret_cast<const us8*>(srow + tid * 8);
  float s[8];
#pragma unroll
  for (int j = 0; j < 8; j++) s[j] = bf2f(sv[j]);

  __shared__ float redm[4], redl[4], redt[4];

  // --- softmax 1: max ---
  float m = s[0];
#pragma unroll
  for (int j = 1; j < 8; j++) m = fmaxf(m, s[j]);
  for (int o = 32; o; o >>= 1) m = fmaxf(m, __shfl_xor(m, o));
  if (lane == 0) redm[wave] = m;
  __syncthreads();
  m = fmaxf(fmaxf(redm[0], redm[1]), fmaxf(redm[2], redm[3]));

  // --- softmax 1: sum ---
  float p[8];
  float ls = 0.0f;
#pragma unroll
  for (int j = 0; j < 8; j++) { p[j] = __expf(s[j] - m); ls += p[j]; }
  for (int o = 32; o; o >>= 1) ls += __shfl_xor(ls, o);
  if (lane == 0) redl[wave] = ls;
  __syncthreads();
  ls = redl[0] + redl[1] + redl[2] + redl[3];
  const float invL = 1.0f / ls;

  // --- mask + softmax 2 (p in [0,1]: no max-sub needed; masked -> exactly 0) ---
  int4 m0 = *reinterpret_cast<const int4*>(mrow + tid * 8);
  int4 m1 = *reinterpret_cast<const int4*>(mrow + tid * 8 + 4);
  const int mk[8] = {m0.x, m0.y, m0.z, m0.w, m1.x, m1.y, m1.z, m1.w};
  float t[8];
  float ts = 0.0f;
#pragma unroll
  for (int j = 0; j < 8; j++) {
    float e = (mk[j] != 0) ? __expf(p[j] * invL) : 0.0f;
    t[j] = e;
    ts += e;
  }
  for (int o = 32; o; o >>= 1) ts += __shfl_xor(ts, o);
  if (lane == 0) redt[wave] = ts;
  __syncthreads();
  ts = redt[0] + redt[1] + redt[2] + redt[3];

  us8 ov;
  if (ts > 0.0f) {
    const float invT = 1.0f / ts;
#pragma unroll
    for (int j = 0; j < 8; j++) ov[j] = f2bf(t[j] * invT);
  } else {  // all-masked row: reference softmax of uniform -1e20 -> 1/N
#pragma unroll
    for (int j = 0; j < 8; j++) ov[j] = f2bf(1.0f / (float)NN);
  }
  *reinterpret_cast<us8*>(wrow + tid * 8) = ov;
}

// ---------------------------------------------------------------------------
extern "C" void kernel_launch(void* const* d_in, const int* in_sizes, int n_in,
                              void* d_out, int out_size, void* d_ws, size_t ws_size,
                              hipStream_t stream) {
  const float* x = (const float*)d_in[0];
  const int* mask = (const int*)d_in[1];
  const float* Wqkv = (const float*)d_in[2];
  const float* bqkv = (const float*)d_in[3];
  const float* Wout = (const float*)d_in[4];
  const float* bout = (const float*)d_in[5];
  float* out = (float*)d_out;

  char* p = (char*)d_ws;
  unsigned short* xb = (unsigned short*)p;    p += (long)16384 * 1024 * 2;   // 33.5MB
  unsigned short* wqkvt = (unsigned short*)p; p += (long)3072 * 1024 * 2;    // 6.3MB
  unsigned short* woutt = (unsigned short*)p; p += (long)1024 * 1024 * 2;    // 2.1MB
  unsigned short* qkv = (unsigned short*)p;   p += (long)16384 * 3072 * 2;   // 100.7MB
  unsigned short* vt = (unsigned short*)p;    p += (long)8 * 1024 * 2048 * 2;// 33.5MB
  unsigned short* attn = (unsigned short*)p;  p += (long)16384 * 1024 * 2;   // 33.5MB
  const long fixed = (long)(p - (char*)d_ws);

  // batch chunk for S/w2 (bf16 [chunk,2048,2048] each); degrade if ws is small
  int chunk = 8;
  while (chunk > 1 && fixed + (long)chunk * NN * NN * 2 * 2 > (long)ws_size) chunk >>= 1;
  unsigned short* S = (unsigned short*)p;  p += (long)chunk * NN * NN * 2;
  unsigned short* w2 = (unsigned short*)p;

  // 1) convert x to bf16; transpose-convert weights
  cvt_bf16<<<4096, 256, 0, stream>>>(x, xb, (long)16384 * 1024);
  transpose_cvt<<<dim3(3072 / 32, 1024 / 32), 256, 0, stream>>>(Wqkv, wqkvt, 1024, 3072);
  transpose_cvt<<<dim3(1024 / 32, 1024 / 32), 256, 0, stream>>>(Wout, woutt, 1024, 1024);

  // 2) QKV projection: [16384,1024] @ [3072,1024]^T + b -> qkv bf16 [16384,3072]
  gemm_bt<true, false><<<dim3(24, 128, 1), 256, 0, stream>>>(
      xb, 1024, 0, wqkvt, 1024, 0, qkv, 3072, 0, bqkv, 1024, 1.0f);

  // 3) V^T per batch for the PV NT-GEMM
  transpose_v<<<dim3(32, 64, 8), 256, 0, stream>>>(qkv, vt);

  // 4) attention per batch-chunk
  for (int b0 = 0; b0 < 8; b0 += chunk) {
    // S = Q @ K^T / 32  (bf16 out)
    gemm_bt<false, false><<<dim3(16, 16, chunk), 256, 0, stream>>>(
        qkv + (long)b0 * NN * 3072, 3072, (long)NN * 3072,
        qkv + (long)b0 * NN * 3072 + 1024, 3072, (long)NN * 3072,
        S, NN, (long)NN * NN, nullptr, 1024, 0.03125f);
    // fused softmax -> mask -> softmax
    softmax2<<<dim3(NN, chunk), 256, 0, stream>>>(S, mask, w2, b0);
    // attn = w2 @ V  ( = w2 @ vt^T )
    gemm_bt<false, false><<<dim3(8, 16, chunk), 256, 0, stream>>>(
        w2, NN, (long)NN * NN,
        vt + (long)b0 * DD * NN, NN, (long)DD * NN,
        attn + (long)b0 * NN * DD, DD, (long)NN * DD, nullptr, 2048, 1.0f);
  }

  // 5) output projection: [16384,1024] @ [1024,1024]^T + b -> fp32 out
  gemm_bt<true, true><<<dim3(8, 128, 1), 256, 0, stream>>>(
      attn, 1024, 0, woutt, 1024, 0, out, 1024, 0, bout, 1024, 1.0f);
}